// Round 5
// baseline (37506.055 us; speedup 1.0000x reference)
//
#include <hip/hip_runtime.h>
#include <hip/hip_bf16.h>
#include <math.h>

// Problem constants: V=32000, D=256, H=256, L=2, C=2, B=64, T=1024, PAD=0
namespace {
constexpr int Bn = 64;
constexpr int Tn = 1024;
constexpr int Dn = 256;
constexpr int Hn = 256;
}

typedef __attribute__((ext_vector_type(8))) short short8;
typedef __attribute__((ext_vector_type(4))) float f32x4;

template <typename T>
__device__ __forceinline__ float ldf(const T* p, long i);
template <>
__device__ __forceinline__ float ldf<float>(const float* p, long i) { return p[i]; }
template <>
__device__ __forceinline__ float ldf<__hip_bfloat16>(const __hip_bfloat16* p, long i) {
  return __bfloat162float(p[i]);
}

__device__ __forceinline__ float sigmf(float x) { return 1.0f / (1.0f + __expf(-x)); }
__device__ __forceinline__ float tanh_fast(float x) {
  return 1.0f - 2.0f / (__expf(2.0f * x) + 1.0f);
}

// ---------------------------------------------------------------------------
// Dtype detector (validated round 2: flag=1 -> f32 inputs).
// ---------------------------------------------------------------------------
__global__ void k_detect(const unsigned short* __restrict__ e, int* __restrict__ flag) {
  __shared__ int sbuf[256];
  int bad = 0;
  for (int i = threadIdx.x; i < 4096; i += 256) {
    const unsigned short v = e[i];
    const int ex = (v >> 7) & 0xFF;
    bad += (ex >= 137) ? 1 : 0;
  }
  sbuf[threadIdx.x] = bad;
  __syncthreads();
  for (int s = 128; s > 0; s >>= 1) {
    if (threadIdx.x < s) sbuf[threadIdx.x] += sbuf[threadIdx.x + s];
    __syncthreads();
  }
  if (threadIdx.x == 0) flag[0] = (sbuf[0] > 64) ? 1 : 0;
}

__global__ void k_lengths(const int* __restrict__ x, int* __restrict__ len) {
  const int b = blockIdx.x;
  int cnt = 0;
  for (int t = threadIdx.x; t < Tn; t += blockDim.x) cnt += (x[b * Tn + t] != 0) ? 1 : 0;
  __shared__ int sbuf[256];
  sbuf[threadIdx.x] = cnt;
  __syncthreads();
  for (int s = 128; s > 0; s >>= 1) {
    if (threadIdx.x < s) sbuf[threadIdx.x] += sbuf[threadIdx.x + s];
    __syncthreads();
  }
  if (threadIdx.x == 0) len[b] = sbuf[0];
}

// ===========================================================================
// FAST PATH
// ===========================================================================

// biases -> f32 [4][1024] (order: f0,b0,f1,b1); zero sync counters + election
// scoreboards (2048 u32 = up to 128 recurrent dispatches).
__global__ void k_prep_small(const void* b0f, const void* b0b, const void* b1f, const void* b1b,
                             const int* __restrict__ flag, float* __restrict__ biasbuf,
                             unsigned* __restrict__ ctr, unsigned* __restrict__ elect) {
  const int tid = threadIdx.x;
  if (tid < 8) ctr[tid] = 0;
  for (int i = tid; i < 2048; i += 256) elect[i] = 0;
  const bool isf32 = flag[0] != 0;
  for (int idx = tid; idx < 4096; idx += 256) {
    const int j = idx >> 10, col = idx & 1023;
    const void* src = (j == 0) ? b0f : (j == 1) ? b0b : (j == 2) ? b1f : b1b;
    biasbuf[idx] = isf32 ? ((const float*)src)[col]
                         : __bfloat162float(((const __hip_bfloat16*)src)[col]);
  }
}

// Transpose+convert W[(H+XK) x 1024] -> WhT bf16 [1024][256], WxT bf16 [1024][XK].
__global__ void k_prepw(const void* W0, const void* W1, const void* W2, const void* W3,
                        const int* __restrict__ flag, __hip_bfloat16* __restrict__ whT,
                        __hip_bfloat16* __restrict__ wxT0, __hip_bfloat16* __restrict__ wxT1) {
  const int j = blockIdx.z;
  const int rows = (j < 2) ? 512 : 768;
  const int bx = blockIdx.x;
  if (bx * 64 >= rows) return;
  const int by = blockIdx.y;
  const void* W = (j == 0) ? W0 : (j == 1) ? W1 : (j == 2) ? W2 : W3;
  const bool isf32 = flag[0] != 0;
  __shared__ float tile[64][65];
  const int tid = threadIdx.x;
  const int c = tid & 63, r4 = tid >> 6;
#pragma unroll
  for (int rep = 0; rep < 16; ++rep) {
    const int rr = r4 * 16 + rep;
    const size_t idx = (size_t)(bx * 64 + rr) * 1024 + by * 64 + c;
    tile[rr][c] = isf32 ? ((const float*)W)[idx]
                        : __bfloat162float(((const __hip_bfloat16*)W)[idx]);
  }
  __syncthreads();
  const int kk = tid & 63;
#pragma unroll
  for (int rep = 0; rep < 16; ++rep) {
    const int a = r4 * 16 + rep;
    const int n = by * 64 + a;
    const int k = bx * 64 + kk;
    const __hip_bfloat16 v = __float2bfloat16(tile[kk][a]);
    if (k < 256) {
      whT[(size_t)j * (1024 * 256) + (size_t)n * 256 + k] = v;
    } else {
      const int k2 = k - 256;
      if (j < 2)
        wxT0[(size_t)j * (1024 * 256) + (size_t)n * 256 + k2] = v;
      else
        wxT1[(size_t)(j - 2) * (1024 * 512) + (size_t)n * 512 + k2] = v;
    }
  }
}

// ---------------------------------------------------------------------------
// Phased xproj GEMM (unchanged from round 4).
// ---------------------------------------------------------------------------
template <int LAYER>
__launch_bounds__(256, 2)
__global__ void k_xproj(const int* __restrict__ x, const void* __restrict__ E,
                        const int* __restrict__ flag, const __hip_bfloat16* __restrict__ seq0,
                        const __hip_bfloat16* __restrict__ WT,  // [2][1024][K]
                        const float* __restrict__ bias,         // [2][1024]
                        float* __restrict__ xp,                 // [2][Tc][64][1024]
                        const int t0f, const int t0b, const int Tc) {
  constexpr int K = (LAYER == 0) ? 256 : 512;
  constexpr int NK = K / 32;
  const int tl = blockIdx.x, by = blockIdx.y, dz = blockIdx.z;
  const int t = (dz ? t0b : t0f) + tl;
  const int tid = threadIdx.x, w = tid >> 6, L = tid & 63, quad = L >> 4, l16 = L & 15;
  const __hip_bfloat16* __restrict__ WTd = WT + (size_t)dz * (1024 * K);
  const float* __restrict__ bsd = bias + dz * 1024;
  float* __restrict__ o = xp + (size_t)(dz * Tc + tl) * (64 * 1024);

  short8 afrag[NK];
  const int bA = w * 16 + l16;
  if constexpr (LAYER == 0) {
    const int tok = x[bA * Tn + t];
    if (flag[0]) {
      const float* __restrict__ er = (const float*)E + (size_t)tok * Dn;
#pragma unroll
      for (int kc = 0; kc < NK; ++kc) {
        short8 a;
#pragma unroll
        for (int jj = 0; jj < 8; ++jj) {
          const __hip_bfloat16 hv = __float2bfloat16(er[kc * 32 + quad * 8 + jj]);
          a[jj] = *(const short*)&hv;
        }
        afrag[kc] = a;
      }
    } else {
      const __hip_bfloat16* __restrict__ er = (const __hip_bfloat16*)E + (size_t)tok * Dn;
#pragma unroll
      for (int kc = 0; kc < NK; ++kc) afrag[kc] = *(const short8*)(er + kc * 32 + quad * 8);
    }
  } else {
    const __hip_bfloat16* __restrict__ ar = seq0 + ((size_t)t * 64 + bA) * 512;
#pragma unroll
    for (int kc = 0; kc < NK; ++kc) afrag[kc] = *(const short8*)(ar + kc * 32 + quad * 8);
  }

  f32x4 acc[4];
#pragma unroll
  for (int nt = 0; nt < 4; ++nt) {
    const float bv = bsd[by * 64 + nt * 16 + l16];
    acc[nt][0] = bv; acc[nt][1] = bv; acc[nt][2] = bv; acc[nt][3] = bv;
  }
#pragma unroll
  for (int kc = 0; kc < NK; ++kc) {
#pragma unroll
    for (int nt = 0; nt < 4; ++nt) {
      const short8 b =
          *(const short8*)(WTd + (size_t)(by * 64 + nt * 16 + l16) * K + kc * 32 + quad * 8);
      acc[nt] = __builtin_amdgcn_mfma_f32_16x16x32_bf16(afrag[kc], b, acc[nt], 0, 0, 0);
    }
  }
#pragma unroll
  for (int nt = 0; nt < 4; ++nt)
#pragma unroll
    for (int r = 0; r < 4; ++r)
      o[(size_t)(w * 16 + quad * 4 + r) * 1024 + by * 64 + nt * 16 + l16] = acc[nt][r];
}

// ---------------------------------------------------------------------------
// Phased recurrent layer with SAME-XCD ELECTION.
// Launch 64 blocks (all co-resident on 256 CUs). Each block reads its physical
// XCD (s_getreg HW_REG_XCC_ID=20), registers in a per-dispatch scoreboard,
// waits for all 64, then the 8 lowest-rank blocks on the most-populated XCD
// (pigeonhole: >=8 of 64) become workers wid=0..7; the rest exit. This puts
// the h-mailbox traffic through ONE shared L2 instead of cross-XCD L3.
// Worker wid: d = wid>>2 (direction), q = wid&3 (64-unit chunk).
// ---------------------------------------------------------------------------
template <bool WRITE_SEQ>
__launch_bounds__(256, 1) __global__
void k_lstm_fast(const __hip_bfloat16* __restrict__ WhT,  // [2][1024][256] this layer
                 const float* __restrict__ xproj,          // [2][Tc][64][1024] f32
                 const int* __restrict__ lengths, unsigned* __restrict__ ctr,  // [2]
                 unsigned* __restrict__ elect,              // [16] this dispatch
                 __hip_bfloat16* __restrict__ hglob,       // [2][2][64][256]
                 float* __restrict__ cstate, float* __restrict__ hstate,  // [2][64][256]
                 __hip_bfloat16* __restrict__ seq0,        // [T][64][512]
                 const int s0, const int Tc) {
  const int tid = threadIdx.x;

  // ---- election ----
  __shared__ int s_wid;
  if (tid == 0) {
    int xcd;
    asm volatile("s_getreg_b32 %0, hwreg(20, 0, 32)" : "=s"(xcd));
    xcd &= 7;
    const unsigned rank =
        __hip_atomic_fetch_add(&elect[xcd], 1u, __ATOMIC_RELAXED, __HIP_MEMORY_SCOPE_AGENT);
    __hip_atomic_fetch_add(&elect[8], 1u, __ATOMIC_RELEASE, __HIP_MEMORY_SCOPE_AGENT);
    while (__hip_atomic_load(&elect[8], __ATOMIC_ACQUIRE, __HIP_MEMORY_SCOPE_AGENT) < 64u)
      __builtin_amdgcn_s_sleep(1);
    unsigned best = 0, bestc = 0;
    for (int i = 0; i < 8; ++i) {
      const unsigned c = __hip_atomic_load(&elect[i], __ATOMIC_RELAXED, __HIP_MEMORY_SCOPE_AGENT);
      if (c > bestc) { bestc = c; best = (unsigned)i; }
    }
    s_wid = ((unsigned)xcd == best && rank < 8u) ? (int)rank : -1;
  }
  __syncthreads();
  const int wid = s_wid;
  if (wid < 0) return;

  const int d = wid >> 2;
  const int q = wid & 3;
  const int w = tid >> 6, L = tid & 63, quad = L >> 4, l16 = L & 15;
  const int u = q * 64 + w * 16 + l16;

  __shared__ __hip_bfloat16 h_lds[64][264];
  for (int idx = tid; idx < 64 * 264; idx += 256) (&h_lds[0][0])[idx] = __float2bfloat16(0.0f);

  const __hip_bfloat16* __restrict__ Wd = WhT + (size_t)d * (1024 * 256);
  short8 wfrag[4][8];
#pragma unroll
  for (int g = 0; g < 4; ++g)
#pragma unroll
    for (int kc = 0; kc < 8; ++kc)
      wfrag[g][kc] = *(const short8*)(Wd + (size_t)(g * 256 + u) * 256 + kc * 32 + quad * 8);

  float c_reg[16], h_reg[16];
  int len_b[16];
#pragma unroll
  for (int mt = 0; mt < 4; ++mt)
#pragma unroll
    for (int r = 0; r < 4; ++r) {
      const int idx = mt * 4 + r;
      const int b = mt * 16 + quad * 4 + r;
      len_b[idx] = lengths[b];
      if (s0 == 0) {
        c_reg[idx] = 0.0f;
        h_reg[idx] = 0.0f;
      } else {
        c_reg[idx] = cstate[((size_t)(d * 64 + b) << 8) + u];
        h_reg[idx] = hstate[((size_t)(d * 64 + b) << 8) + u];
      }
    }
  unsigned* myctr = ctr + d;
  __hip_bfloat16* __restrict__ hg = hglob + (size_t)d * (2 * 64 * 256);
  __syncthreads();

  for (int sl = 0; sl < Tc; ++sl) {
    const int s = s0 + sl;
    const int t = d ? (Tn - 1 - s) : s;
    const int tl = d ? (Tc - 1 - sl) : sl;

    // 1. C-init from xproj (issued before the spin -> latency hidden)
    f32x4 acc[4][4];
#pragma unroll
    for (int mt = 0; mt < 4; ++mt) {
      const float* __restrict__ xrow =
          xproj + ((size_t)(d * Tc + tl) * 64 + mt * 16 + quad * 4) * 1024 + u;
#pragma unroll
      for (int g = 0; g < 4; ++g)
#pragma unroll
        for (int r = 0; r < 4; ++r) acc[mt][g][r] = xrow[(size_t)r * 1024 + g * 256];
    }

    // 2. finish previous step's h exchange
    if (s > 0) {
      if (tid == 0) {
        while (__hip_atomic_load(myctr, __ATOMIC_RELAXED, __HIP_MEMORY_SCOPE_AGENT) <
               4u * (unsigned)s)
          __builtin_amdgcn_s_sleep(1);
      }
      __syncthreads();
      __threadfence();  // acquire
      const __hip_bfloat16* __restrict__ src = hg + ((s - 1) & 1) * (64 * 256);
#pragma unroll
      for (int i = 0; i < 8; ++i) {
        const int flat = i * 256 + tid;
        const int b = flat >> 5, c8 = (flat & 31) * 8;
        *(short8*)&h_lds[b][c8] = *(const short8*)(src + b * 256 + c8);
      }
      __syncthreads();
    }

    // 3. z += h @ Wh
#pragma unroll
    for (int kc = 0; kc < 8; ++kc) {
#pragma unroll
      for (int mt = 0; mt < 4; ++mt) {
        const short8 a = *(const short8*)&h_lds[mt * 16 + l16][kc * 32 + quad * 8];
#pragma unroll
        for (int g = 0; g < 4; ++g)
          acc[mt][g] =
              __builtin_amdgcn_mfma_f32_16x16x32_bf16(a, wfrag[g][kc], acc[mt][g], 0, 0, 0);
      }
    }

    // 4. gates + state update (lane-local)
    __hip_bfloat16* __restrict__ dst = hg + (s & 1) * (64 * 256);
#pragma unroll
    for (int mt = 0; mt < 4; ++mt)
#pragma unroll
      for (int r = 0; r < 4; ++r) {
        const int idx = mt * 4 + r, b = mt * 16 + quad * 4 + r;
        const float fg = sigmf(acc[mt][0][r]);
        const float ig = sigmf(acc[mt][1][r]);
        const float gg = tanh_fast(acc[mt][2][r]);
        const float og = sigmf(acc[mt][3][r]);
        const float cn = fg * c_reg[idx] + ig * gg;
        const float hn = og * tanh_fast(cn);
        if (t < len_b[idx]) {
          c_reg[idx] = cn;
          h_reg[idx] = hn;
        }
        dst[b * 256 + u] = __float2bfloat16(h_reg[idx]);
        if (WRITE_SEQ)
          seq0[((size_t)t * 64 + b) * 512 + d * 256 + u] = __float2bfloat16(h_reg[idx]);
      }

    // 5. publish
    __threadfence();  // release
    __syncthreads();
    if (tid == 0) __hip_atomic_fetch_add(myctr, 1u, __ATOMIC_RELEASE, __HIP_MEMORY_SCOPE_AGENT);
  }

  // save h/c for the next phase (hstate doubles as hfin for the last layer)
#pragma unroll
  for (int mt = 0; mt < 4; ++mt)
#pragma unroll
    for (int r = 0; r < 4; ++r) {
      const int idx = mt * 4 + r, b = mt * 16 + quad * 4 + r;
      cstate[((size_t)(d * 64 + b) << 8) + u] = c_reg[idx];
      hstate[((size_t)(d * 64 + b) << 8) + u] = h_reg[idx];
    }
}

// ===========================================================================
// SLOW FALLBACK PATH (round-2 passing version, used when ws is too small)
// ===========================================================================
template <typename TW, int XK, bool WRITE_SEQ>
__device__ __forceinline__ void lstm_body(const int* __restrict__ x, const TW* __restrict__ E,
                                          const __hip_bfloat16* __restrict__ seq_in,
                                          const TW* __restrict__ W, const TW* __restrict__ bias,
                                          const int len, const int b, const int dir,
                                          __hip_bfloat16* __restrict__ seq_out,
                                          float* __restrict__ hfin) {
  const int j = threadIdx.x;
  __shared__ float h[Hn];
  __shared__ float xb[XK];
  float hj = 0.0f, cj = 0.0f;
  h[j] = 0.0f;
  const float bfj = ldf(bias, j);
  const float bij = ldf(bias, Hn + j);
  const float bgj = ldf(bias, 2 * Hn + j);
  const float boj = ldf(bias, 3 * Hn + j);
  __syncthreads();
  for (int s = 0; s < Tn; ++s) {
    const int t = dir ? (Tn - 1 - s) : s;
    const bool active = (t < len);
    if (active) {
      if constexpr (XK == Dn) {
        const int tok = x[b * Tn + t];
        xb[j] = ldf(E, (long)tok * Dn + j);
      } else {
        const long base = ((long)(b * Tn + t)) * (2 * Hn);
        xb[j] = __bfloat162float(seq_in[base + j]);
        xb[j + Hn] = __bfloat162float(seq_in[base + j + Hn]);
      }
      __syncthreads();
      float af = bfj, ai = bij, ag = bgj, ao = boj;
#pragma unroll 4
      for (int k = 0; k < Hn; ++k) {
        const float hk = h[k];
        const long r = (long)k * (4 * Hn);
        af += hk * ldf(W, r + j);
        ai += hk * ldf(W, r + Hn + j);
        ag += hk * ldf(W, r + 2 * Hn + j);
        ao += hk * ldf(W, r + 3 * Hn + j);
      }
#pragma unroll 4
      for (int k = 0; k < XK; ++k) {
        const float xk = xb[k];
        const long r = (long)(Hn + k) * (4 * Hn);
        af += xk * ldf(W, r + j);
        ai += xk * ldf(W, r + Hn + j);
        ag += xk * ldf(W, r + 2 * Hn + j);
        ao += xk * ldf(W, r + 3 * Hn + j);
      }
      const float fg = 1.0f / (1.0f + expf(-af));
      const float ig = 1.0f / (1.0f + expf(-ai));
      const float gg = tanhf(ag);
      const float og = 1.0f / (1.0f + expf(-ao));
      const float cn = fg * cj + ig * gg;
      const float hn = og * tanhf(cn);
      __syncthreads();
      hj = hn;
      cj = cn;
      h[j] = hn;
      __syncthreads();
    }
    if constexpr (WRITE_SEQ) {
      seq_out[((long)(b * Tn + t)) * (2 * Hn) + dir * Hn + j] = __float2bfloat16(hj);
    }
  }
  if constexpr (!WRITE_SEQ) hfin[(dir * Bn + b) * Hn + j] = hj;
}

template <int XK, bool WRITE_SEQ>
__global__ void k_lstm(const int* __restrict__ x, const void* __restrict__ E,
                       const __hip_bfloat16* __restrict__ seq_in, const void* __restrict__ Wf,
                       const void* __restrict__ bf, const void* __restrict__ Wb,
                       const void* __restrict__ bb, const int* __restrict__ lengths,
                       const int* __restrict__ flag, __hip_bfloat16* __restrict__ seq_out,
                       float* __restrict__ hfin) {
  const int b = blockIdx.x & (Bn - 1);
  const int dir = blockIdx.x >> 6;
  const int len = lengths[b];
  const void* W = dir ? Wb : Wf;
  const void* bias = dir ? bb : bf;
  if (flag[0]) {
    lstm_body<float, XK, WRITE_SEQ>(x, (const float*)E, seq_in, (const float*)W,
                                    (const float*)bias, len, b, dir, seq_out, hfin);
  } else {
    lstm_body<__hip_bfloat16, XK, WRITE_SEQ>(x, (const __hip_bfloat16*)E, seq_in,
                                             (const __hip_bfloat16*)W, (const __hip_bfloat16*)bias,
                                             len, b, dir, seq_out, hfin);
  }
}

// ---------------------------------------------------------------------------
template <typename TW>
__device__ __forceinline__ void fc_body(const float* __restrict__ hfin, const TW* __restrict__ Wfc,
                                        const TW* __restrict__ bfc, TW* __restrict__ out) {
  const int idx = threadIdx.x;
  const int b = idx >> 1;
  const int cc = idx & 1;
  float acc = ldf(bfc, cc);
  for (int k = 0; k < Hn; ++k) acc += hfin[(0 * Bn + b) * Hn + k] * ldf(Wfc, k * 2 + cc);
  for (int k = 0; k < Hn; ++k) acc += hfin[(1 * Bn + b) * Hn + k] * ldf(Wfc, (Hn + k) * 2 + cc);
  if constexpr (sizeof(TW) == 2) {
    out[b * 2 + cc] = __float2bfloat16(acc);
  } else {
    out[b * 2 + cc] = acc;
  }
}

__global__ void k_fc(const float* __restrict__ hfin, const void* __restrict__ Wfc,
                     const void* __restrict__ bfc, const int* __restrict__ flag,
                     void* __restrict__ out) {
  if (flag[0]) {
    fc_body<float>(hfin, (const float*)Wfc, (const float*)bfc, (float*)out);
  } else {
    fc_body<__hip_bfloat16>(hfin, (const __hip_bfloat16*)Wfc, (const __hip_bfloat16*)bfc,
                            (__hip_bfloat16*)out);
  }
}

// ---------------------------------------------------------------------------
extern "C" void kernel_launch(void* const* d_in, const int* in_sizes, int n_in,
                              void* d_out, int out_size, void* d_ws, size_t ws_size,
                              hipStream_t stream) {
  const int* x = (const int*)d_in[0];
  const void* E = d_in[1];
  const void* Wf0 = d_in[2];
  const void* bf0 = d_in[3];
  const void* Wb0 = d_in[4];
  const void* bb0 = d_in[5];
  const void* Wf1 = d_in[6];
  const void* bf1 = d_in[7];
  const void* Wb1 = d_in[8];
  const void* bb1 = d_in[9];
  const void* Wfc = d_in[10];
  const void* bfc = d_in[11];

  char* ws = (char*)d_ws;
  int* flag = (int*)ws;                  // @0
  unsigned* ctr = (unsigned*)(ws + 64);  // 8 u32
  int* lengths = (int*)(ws + 256);
  unsigned* elect = (unsigned*)(ws + 32 * 1024);  // 2048 u32 (16 per dispatch)

  const size_t MB = 1ull << 20;
  const size_t KB = 1024;

  k_detect<<<1, 256, 0, stream>>>((const unsigned short*)E, flag);
  k_lengths<<<Bn, 256, 0, stream>>>(x, lengths);

  // pick largest xproj chunk (Tc timesteps/dir, Tc*0.5 MB) that fits ws
  int Tc = 0;
  {
    const size_t fixed = 71 * MB + MB;  // weights/state/seq0 + slack
    const int cands[7] = {1024, 512, 256, 128, 64, 32, 16};
    for (int i = 0; i < 7; ++i)
      if (fixed + (size_t)cands[i] * 512 * KB <= ws_size) { Tc = cands[i]; break; }
  }

  if (Tc > 0) {
    float* biasbuf = (float*)(ws + 4096);                    // 16 KB
    __hip_bfloat16* whT = (__hip_bfloat16*)(ws + 1 * MB);    // [4][1024][256] = 2 MB
    __hip_bfloat16* wxT0 = (__hip_bfloat16*)(ws + 3 * MB);   // [2][1024][256] = 1 MB
    __hip_bfloat16* wxT1 = (__hip_bfloat16*)(ws + 4 * MB);   // [2][1024][512] = 2 MB
    __hip_bfloat16* hglob = (__hip_bfloat16*)(ws + 6 * MB);  // 128 KB
    float* cstate0 = (float*)(ws + 6 * MB + 128 * KB);       // 128 KB
    float* hstate0 = (float*)(ws + 6 * MB + 256 * KB);       // 128 KB
    float* cstate1 = (float*)(ws + 6 * MB + 384 * KB);       // 128 KB
    float* hstate1 = (float*)(ws + 6 * MB + 512 * KB);       // 128 KB
    __hip_bfloat16* seq0 = (__hip_bfloat16*)(ws + 7 * MB);   // [1024][64][512] = 64 MB
    float* xproj = (float*)(ws + 71 * MB);                   // [2][Tc][64][1024] f32

    k_prep_small<<<1, 256, 0, stream>>>(bf0, bb0, bf1, bb1, flag, biasbuf, ctr, elect);
    k_prepw<<<dim3(12, 16, 4), 256, 0, stream>>>(Wf0, Wb0, Wf1, Wb1, flag, whT, wxT0, wxT1);

    const int P = Tn / Tc;
    // layer 0
    for (int p = 0; p < P; ++p) {
      const int s0 = p * Tc;
      const int t0f = s0, t0b = Tn - s0 - Tc;
      k_xproj<0><<<dim3(Tc, 16, 2), 256, 0, stream>>>(x, E, flag, nullptr, wxT0, biasbuf, xproj,
                                                      t0f, t0b, Tc);
      k_lstm_fast<true><<<64, 256, 0, stream>>>(whT, xproj, lengths, ctr, elect + 16 * p, hglob,
                                                cstate0, hstate0, seq0, s0, Tc);
    }
    // layer 1
    for (int p = 0; p < P; ++p) {
      const int s0 = p * Tc;
      const int t0f = s0, t0b = Tn - s0 - Tc;
      k_xproj<1><<<dim3(Tc, 16, 2), 256, 0, stream>>>(x, E, flag, seq0, wxT1, biasbuf + 2048,
                                                      xproj, t0f, t0b, Tc);
      k_lstm_fast<false><<<64, 256, 0, stream>>>(whT + 2 * 1024 * 256, xproj, lengths, ctr + 2,
                                                 elect + 16 * (P + p), hglob, cstate1, hstate1,
                                                 nullptr, s0, Tc);
    }
    k_fc<<<1, 128, 0, stream>>>(hstate1, Wfc, bfc, flag, d_out);
  } else {
    // slow fallback (round-2 passing path)
    __hip_bfloat16* seq0 = (__hip_bfloat16*)(ws + 64 * 1024);
    const size_t seq0_bytes = (size_t)Bn * Tn * 2 * Hn * sizeof(__hip_bfloat16);
    float* hfin = (float*)(ws + 64 * 1024 + seq0_bytes);
    k_lstm<Dn, true><<<2 * Bn, 256, 0, stream>>>(x, E, nullptr, Wf0, bf0, Wb0, bb0, lengths, flag,
                                                 seq0, nullptr);
    k_lstm<2 * Hn, false><<<2 * Bn, 256, 0, stream>>>(x, E, seq0, Wf1, bf1, Wb1, bb1, lengths,
                                                      flag, nullptr, hfin);
    k_fc<<<1, 128, 0, stream>>>(hfin, Wfc, bfc, flag, d_out);
  }
}

// Round 6
// 20331.699 us; speedup vs baseline: 1.8447x; 1.8447x over previous
//
#include <hip/hip_runtime.h>
#include <hip/hip_bf16.h>
#include <math.h>

// Problem constants: V=32000, D=256, H=256, L=2, C=2, B=64, T=1024, PAD=0
namespace {
constexpr int Bn = 64;
constexpr int Tn = 1024;
constexpr int Dn = 256;
constexpr int Hn = 256;
}

typedef __attribute__((ext_vector_type(8))) short short8;
typedef __attribute__((ext_vector_type(4))) float f32x4;

template <typename T>
__device__ __forceinline__ float ldf(const T* p, long i);
template <>
__device__ __forceinline__ float ldf<float>(const float* p, long i) { return p[i]; }
template <>
__device__ __forceinline__ float ldf<__hip_bfloat16>(const __hip_bfloat16* p, long i) {
  return __bfloat162float(p[i]);
}

__device__ __forceinline__ float sigmf(float x) { return 1.0f / (1.0f + __expf(-x)); }
__device__ __forceinline__ float tanh_fast(float x) {
  return 1.0f - 2.0f / (__expf(2.0f * x) + 1.0f);
}

// ---------------------------------------------------------------------------
// Dtype detector (validated round 2: flag=1 -> f32 inputs).
// ---------------------------------------------------------------------------
__global__ void k_detect(const unsigned short* __restrict__ e, int* __restrict__ flag) {
  __shared__ int sbuf[256];
  int bad = 0;
  for (int i = threadIdx.x; i < 4096; i += 256) {
    const unsigned short v = e[i];
    const int ex = (v >> 7) & 0xFF;
    bad += (ex >= 137) ? 1 : 0;
  }
  sbuf[threadIdx.x] = bad;
  __syncthreads();
  for (int s = 128; s > 0; s >>= 1) {
    if (threadIdx.x < s) sbuf[threadIdx.x] += sbuf[threadIdx.x + s];
    __syncthreads();
  }
  if (threadIdx.x == 0) flag[0] = (sbuf[0] > 64) ? 1 : 0;
}

__global__ void k_lengths(const int* __restrict__ x, int* __restrict__ len) {
  const int b = blockIdx.x;
  int cnt = 0;
  for (int t = threadIdx.x; t < Tn; t += blockDim.x) cnt += (x[b * Tn + t] != 0) ? 1 : 0;
  __shared__ int sbuf[256];
  sbuf[threadIdx.x] = cnt;
  __syncthreads();
  for (int s = 128; s > 0; s >>= 1) {
    if (threadIdx.x < s) sbuf[threadIdx.x] += sbuf[threadIdx.x + s];
    __syncthreads();
  }
  if (threadIdx.x == 0) len[b] = sbuf[0];
}

// ===========================================================================
// FAST PATH
// ===========================================================================

// biases -> f32 [4][1024] (order: f0,b0,f1,b1).
__global__ void k_prep_small(const void* b0f, const void* b0b, const void* b1f, const void* b1b,
                             const int* __restrict__ flag, float* __restrict__ biasbuf) {
  const int tid = threadIdx.x;
  const bool isf32 = flag[0] != 0;
  for (int idx = tid; idx < 4096; idx += 256) {
    const int j = idx >> 10, col = idx & 1023;
    const void* src = (j == 0) ? b0f : (j == 1) ? b0b : (j == 2) ? b1f : b1b;
    biasbuf[idx] = isf32 ? ((const float*)src)[col]
                         : __bfloat162float(((const __hip_bfloat16*)src)[col]);
  }
}

// Transpose+convert W[(H+XK) x 1024] -> WhT bf16 [1024][256], WxT bf16 [1024][XK].
__global__ void k_prepw(const void* W0, const void* W1, const void* W2, const void* W3,
                        const int* __restrict__ flag, __hip_bfloat16* __restrict__ whT,
                        __hip_bfloat16* __restrict__ wxT0, __hip_bfloat16* __restrict__ wxT1) {
  const int j = blockIdx.z;
  const int rows = (j < 2) ? 512 : 768;
  const int bx = blockIdx.x;
  if (bx * 64 >= rows) return;
  const int by = blockIdx.y;
  const void* W = (j == 0) ? W0 : (j == 1) ? W1 : (j == 2) ? W2 : W3;
  const bool isf32 = flag[0] != 0;
  __shared__ float tile[64][65];
  const int tid = threadIdx.x;
  const int c = tid & 63, r4 = tid >> 6;
#pragma unroll
  for (int rep = 0; rep < 16; ++rep) {
    const int rr = r4 * 16 + rep;
    const size_t idx = (size_t)(bx * 64 + rr) * 1024 + by * 64 + c;
    tile[rr][c] = isf32 ? ((const float*)W)[idx]
                        : __bfloat162float(((const __hip_bfloat16*)W)[idx]);
  }
  __syncthreads();
  const int kk = tid & 63;
#pragma unroll
  for (int rep = 0; rep < 16; ++rep) {
    const int a = r4 * 16 + rep;
    const int n = by * 64 + a;
    const int k = bx * 64 + kk;
    const __hip_bfloat16 v = __float2bfloat16(tile[kk][a]);
    if (k < 256) {
      whT[(size_t)j * (1024 * 256) + (size_t)n * 256 + k] = v;
    } else {
      const int k2 = k - 256;
      if (j < 2)
        wxT0[(size_t)j * (1024 * 256) + (size_t)n * 256 + k2] = v;
      else
        wxT1[(size_t)(j - 2) * (1024 * 512) + (size_t)n * 512 + k2] = v;
    }
  }
}

// ---------------------------------------------------------------------------
// Phased xproj GEMM (unchanged from round 4).
// ---------------------------------------------------------------------------
template <int LAYER>
__launch_bounds__(256, 2)
__global__ void k_xproj(const int* __restrict__ x, const void* __restrict__ E,
                        const int* __restrict__ flag, const __hip_bfloat16* __restrict__ seq0,
                        const __hip_bfloat16* __restrict__ WT,  // [2][1024][K]
                        const float* __restrict__ bias,         // [2][1024]
                        float* __restrict__ xp,                 // [2][Tc][64][1024]
                        const int t0f, const int t0b, const int Tc) {
  constexpr int K = (LAYER == 0) ? 256 : 512;
  constexpr int NK = K / 32;
  const int tl = blockIdx.x, by = blockIdx.y, dz = blockIdx.z;
  const int t = (dz ? t0b : t0f) + tl;
  const int tid = threadIdx.x, w = tid >> 6, L = tid & 63, quad = L >> 4, l16 = L & 15;
  const __hip_bfloat16* __restrict__ WTd = WT + (size_t)dz * (1024 * K);
  const float* __restrict__ bsd = bias + dz * 1024;
  float* __restrict__ o = xp + (size_t)(dz * Tc + tl) * (64 * 1024);

  short8 afrag[NK];
  const int bA = w * 16 + l16;
  if constexpr (LAYER == 0) {
    const int tok = x[bA * Tn + t];
    if (flag[0]) {
      const float* __restrict__ er = (const float*)E + (size_t)tok * Dn;
#pragma unroll
      for (int kc = 0; kc < NK; ++kc) {
        short8 a;
#pragma unroll
        for (int jj = 0; jj < 8; ++jj) {
          const __hip_bfloat16 hv = __float2bfloat16(er[kc * 32 + quad * 8 + jj]);
          a[jj] = *(const short*)&hv;
        }
        afrag[kc] = a;
      }
    } else {
      const __hip_bfloat16* __restrict__ er = (const __hip_bfloat16*)E + (size_t)tok * Dn;
#pragma unroll
      for (int kc = 0; kc < NK; ++kc) afrag[kc] = *(const short8*)(er + kc * 32 + quad * 8);
    }
  } else {
    const __hip_bfloat16* __restrict__ ar = seq0 + ((size_t)t * 64 + bA) * 512;
#pragma unroll
    for (int kc = 0; kc < NK; ++kc) afrag[kc] = *(const short8*)(ar + kc * 32 + quad * 8);
  }

  f32x4 acc[4];
#pragma unroll
  for (int nt = 0; nt < 4; ++nt) {
    const float bv = bsd[by * 64 + nt * 16 + l16];
    acc[nt][0] = bv; acc[nt][1] = bv; acc[nt][2] = bv; acc[nt][3] = bv;
  }
#pragma unroll
  for (int kc = 0; kc < NK; ++kc) {
#pragma unroll
    for (int nt = 0; nt < 4; ++nt) {
      const short8 b =
          *(const short8*)(WTd + (size_t)(by * 64 + nt * 16 + l16) * K + kc * 32 + quad * 8);
      acc[nt] = __builtin_amdgcn_mfma_f32_16x16x32_bf16(afrag[kc], b, acc[nt], 0, 0, 0);
    }
  }
#pragma unroll
  for (int nt = 0; nt < 4; ++nt)
#pragma unroll
    for (int r = 0; r < 4; ++r)
      o[(size_t)(w * 16 + quad * 4 + r) * 1024 + by * 64 + nt * 16 + l16] = acc[nt][r];
}

// ---------------------------------------------------------------------------
// Phased recurrent layer, split-wait sync. 8 blocks: blockIdx.x = d*4+q.
// Block (d,q) owns units [q*64, q*64+64); lane holds z_f,i,g,o of unit
// u = q*64 + w*16 + (L&15) for 16 batches. Wh register-resident.
// Sync: per-(dir,step,block) flag on its own cacheline (release store, no RMW).
// Mailbox: hgs[dir][parity][q][64 b][64 u] bf16 (8 KB per writer, contiguous).
// Wave w polls peer w's flag and copies only that slice; the block's own h
// goes straight to LDS from registers (never read back from global).
// ---------------------------------------------------------------------------
template <bool WRITE_SEQ>
__launch_bounds__(256, 1) __global__
void k_lstm_fast(const __hip_bfloat16* __restrict__ WhT,  // [2][1024][256] this layer
                 const float* __restrict__ xproj,          // [2][Tc][64][1024] f32
                 const int* __restrict__ lengths,
                 unsigned* __restrict__ flags,  // [2 dir][Tn][4 q][16] u32 (64B/flag)
                 __hip_bfloat16* __restrict__ hgs,         // [2][2][4][64][64]
                 float* __restrict__ cstate, float* __restrict__ hstate,  // [2][64][256]
                 __hip_bfloat16* __restrict__ seq0,        // [T][64][512]
                 const int s0, const int Tc) {
  const int d = blockIdx.x >> 2;
  const int q = blockIdx.x & 3;
  const int tid = threadIdx.x;
  const int w = tid >> 6, L = tid & 63, quad = L >> 4, l16 = L & 15;
  const int u = q * 64 + w * 16 + l16;

  __shared__ __hip_bfloat16 h_lds[64][272];  // stride 272 shorts: 16B-aligned rows
  for (int idx = tid; idx < 64 * 272; idx += 256) (&h_lds[0][0])[idx] = __float2bfloat16(0.0f);

  const __hip_bfloat16* __restrict__ Wd = WhT + (size_t)d * (1024 * 256);
  short8 wfrag[4][8];
#pragma unroll
  for (int g = 0; g < 4; ++g)
#pragma unroll
    for (int kc = 0; kc < 8; ++kc)
      wfrag[g][kc] = *(const short8*)(Wd + (size_t)(g * 256 + u) * 256 + kc * 32 + quad * 8);

  float c_reg[16], h_reg[16];
  int len_b[16];
#pragma unroll
  for (int mt = 0; mt < 4; ++mt)
#pragma unroll
    for (int r = 0; r < 4; ++r) {
      const int idx = mt * 4 + r;
      const int b = mt * 16 + quad * 4 + r;
      len_b[idx] = lengths[b];
      if (s0 == 0) {
        c_reg[idx] = 0.0f;
        h_reg[idx] = 0.0f;
      } else {
        c_reg[idx] = cstate[((size_t)(d * 64 + b) << 8) + u];
        h_reg[idx] = hstate[((size_t)(d * 64 + b) << 8) + u];
      }
    }
  __syncthreads();

  for (int sl = 0; sl < Tc; ++sl) {
    const int s = s0 + sl;
    const int t = d ? (Tn - 1 - s) : s;
    const int tl = d ? (Tc - 1 - sl) : sl;

    // 1. C-init from xproj (issued before the wait -> latency hidden)
    f32x4 acc[4][4];
#pragma unroll
    for (int mt = 0; mt < 4; ++mt) {
      const float* __restrict__ xrow =
          xproj + ((size_t)(d * Tc + tl) * 64 + mt * 16 + quad * 4) * 1024 + u;
#pragma unroll
      for (int g = 0; g < 4; ++g)
#pragma unroll
        for (int r = 0; r < 4; ++r) acc[mt][g][r] = xrow[(size_t)r * 1024 + g * 256];
    }

    // 2. split-wait: wave w polls peer w's flag, copies 8 KB slice w.
    //    Own slice (w==q) already in LDS, except on the first step of a
    //    resumed phase (fresh LDS).
    if (s > 0) {
      const bool doload = (w != q) || (sl == 0 && s0 > 0);
      if (doload) {
        const unsigned* fp = flags + ((size_t)(d * Tn + (s - 1)) * 4 + w) * 16;
        const unsigned tag = (unsigned)s;  // (s-1)+1
        while (__hip_atomic_load(fp, __ATOMIC_RELAXED, __HIP_MEMORY_SCOPE_AGENT) < tag)
          __builtin_amdgcn_s_sleep(1);
        __threadfence();  // acquire
        const __hip_bfloat16* __restrict__ src =
            hgs + ((((size_t)d * 2 + ((s - 1) & 1)) * 4 + w) << 12);
#pragma unroll
        for (int c = 0; c < 8; ++c) {
          const short8 v = *(const short8*)(src + c * 512 + L * 8);
          *(short8*)&h_lds[c * 8 + (L >> 3)][w * 64 + (L & 7) * 8] = v;
        }
      }
      __syncthreads();
    }

    // 3. z += h @ Wh
#pragma unroll
    for (int kc = 0; kc < 8; ++kc) {
#pragma unroll
      for (int mt = 0; mt < 4; ++mt) {
        const short8 a = *(const short8*)&h_lds[mt * 16 + l16][kc * 32 + quad * 8];
#pragma unroll
        for (int g = 0; g < 4; ++g)
          acc[mt][g] =
              __builtin_amdgcn_mfma_f32_16x16x32_bf16(a, wfrag[g][kc], acc[mt][g], 0, 0, 0);
      }
    }

    // 4. gates + state update (lane-local), store own mailbox slice ASAP
    __hip_bfloat16* __restrict__ dst = hgs + ((((size_t)d * 2 + (s & 1)) * 4 + q) << 12);
    __hip_bfloat16 hbf[16];
#pragma unroll
    for (int mt = 0; mt < 4; ++mt)
#pragma unroll
      for (int r = 0; r < 4; ++r) {
        const int idx = mt * 4 + r, b = mt * 16 + quad * 4 + r;
        const float fg = sigmf(acc[mt][0][r]);
        const float ig = sigmf(acc[mt][1][r]);
        const float gg = tanh_fast(acc[mt][2][r]);
        const float og = sigmf(acc[mt][3][r]);
        const float cn = fg * c_reg[idx] + ig * gg;
        const float hn = og * tanh_fast(cn);
        if (t < len_b[idx]) {
          c_reg[idx] = cn;
          h_reg[idx] = hn;
        }
        hbf[idx] = __float2bfloat16(h_reg[idx]);
        dst[b * 64 + w * 16 + l16] = hbf[idx];
      }

    // 5. publish: fence + flag (release), then off-critical-path writes
    __threadfence();  // release: drain mailbox stores to coherence point
    __syncthreads();
    if (tid == 0)
      __hip_atomic_store(&flags[((size_t)(d * Tn + s) * 4 + q) * 16], (unsigned)(s + 1),
                         __ATOMIC_RELEASE, __HIP_MEMORY_SCOPE_AGENT);

    // own h -> LDS for next step (no global round-trip)
#pragma unroll
    for (int mt = 0; mt < 4; ++mt)
#pragma unroll
      for (int r = 0; r < 4; ++r)
        h_lds[mt * 16 + quad * 4 + r][u] = hbf[mt * 4 + r];

    if (WRITE_SEQ) {
#pragma unroll
      for (int mt = 0; mt < 4; ++mt)
#pragma unroll
        for (int r = 0; r < 4; ++r) {
          const int b = mt * 16 + quad * 4 + r;
          seq0[((size_t)t * 64 + b) * 512 + d * 256 + u] = hbf[mt * 4 + r];
        }
    }
  }

  // save h/c for the next phase (hstate doubles as hfin for the last layer)
#pragma unroll
  for (int mt = 0; mt < 4; ++mt)
#pragma unroll
    for (int r = 0; r < 4; ++r) {
      const int idx = mt * 4 + r, b = mt * 16 + quad * 4 + r;
      cstate[((size_t)(d * 64 + b) << 8) + u] = c_reg[idx];
      hstate[((size_t)(d * 64 + b) << 8) + u] = h_reg[idx];
    }
}

// ===========================================================================
// SLOW FALLBACK PATH (round-2 passing version, used when ws is too small)
// ===========================================================================
template <typename TW, int XK, bool WRITE_SEQ>
__device__ __forceinline__ void lstm_body(const int* __restrict__ x, const TW* __restrict__ E,
                                          const __hip_bfloat16* __restrict__ seq_in,
                                          const TW* __restrict__ W, const TW* __restrict__ bias,
                                          const int len, const int b, const int dir,
                                          __hip_bfloat16* __restrict__ seq_out,
                                          float* __restrict__ hfin) {
  const int j = threadIdx.x;
  __shared__ float h[Hn];
  __shared__ float xb[XK];
  float hj = 0.0f, cj = 0.0f;
  h[j] = 0.0f;
  const float bfj = ldf(bias, j);
  const float bij = ldf(bias, Hn + j);
  const float bgj = ldf(bias, 2 * Hn + j);
  const float boj = ldf(bias, 3 * Hn + j);
  __syncthreads();
  for (int s = 0; s < Tn; ++s) {
    const int t = dir ? (Tn - 1 - s) : s;
    const bool active = (t < len);
    if (active) {
      if constexpr (XK == Dn) {
        const int tok = x[b * Tn + t];
        xb[j] = ldf(E, (long)tok * Dn + j);
      } else {
        const long base = ((long)(b * Tn + t)) * (2 * Hn);
        xb[j] = __bfloat162float(seq_in[base + j]);
        xb[j + Hn] = __bfloat162float(seq_in[base + j + Hn]);
      }
      __syncthreads();
      float af = bfj, ai = bij, ag = bgj, ao = boj;
#pragma unroll 4
      for (int k = 0; k < Hn; ++k) {
        const float hk = h[k];
        const long r = (long)k * (4 * Hn);
        af += hk * ldf(W, r + j);
        ai += hk * ldf(W, r + Hn + j);
        ag += hk * ldf(W, r + 2 * Hn + j);
        ao += hk * ldf(W, r + 3 * Hn + j);
      }
#pragma unroll 4
      for (int k = 0; k < XK; ++k) {
        const float xk = xb[k];
        const long r = (long)(Hn + k) * (4 * Hn);
        af += xk * ldf(W, r + j);
        ai += xk * ldf(W, r + Hn + j);
        ag += xk * ldf(W, r + 2 * Hn + j);
        ao += xk * ldf(W, r + 3 * Hn + j);
      }
      const float fg = 1.0f / (1.0f + expf(-af));
      const float ig = 1.0f / (1.0f + expf(-ai));
      const float gg = tanhf(ag);
      const float og = 1.0f / (1.0f + expf(-ao));
      const float cn = fg * cj + ig * gg;
      const float hn = og * tanhf(cn);
      __syncthreads();
      hj = hn;
      cj = cn;
      h[j] = hn;
      __syncthreads();
    }
    if constexpr (WRITE_SEQ) {
      seq_out[((long)(b * Tn + t)) * (2 * Hn) + dir * Hn + j] = __float2bfloat16(hj);
    }
  }
  if constexpr (!WRITE_SEQ) hfin[(dir * Bn + b) * Hn + j] = hj;
}

template <int XK, bool WRITE_SEQ>
__global__ void k_lstm(const int* __restrict__ x, const void* __restrict__ E,
                       const __hip_bfloat16* __restrict__ seq_in, const void* __restrict__ Wf,
                       const void* __restrict__ bf, const void* __restrict__ Wb,
                       const void* __restrict__ bb, const int* __restrict__ lengths,
                       const int* __restrict__ flag, __hip_bfloat16* __restrict__ seq_out,
                       float* __restrict__ hfin) {
  const int b = blockIdx.x & (Bn - 1);
  const int dir = blockIdx.x >> 6;
  const int len = lengths[b];
  const void* W = dir ? Wb : Wf;
  const void* bias = dir ? bb : bf;
  if (flag[0]) {
    lstm_body<float, XK, WRITE_SEQ>(x, (const float*)E, seq_in, (const float*)W,
                                    (const float*)bias, len, b, dir, seq_out, hfin);
  } else {
    lstm_body<__hip_bfloat16, XK, WRITE_SEQ>(x, (const __hip_bfloat16*)E, seq_in,
                                             (const __hip_bfloat16*)W, (const __hip_bfloat16*)bias,
                                             len, b, dir, seq_out, hfin);
  }
}

// ---------------------------------------------------------------------------
template <typename TW>
__device__ __forceinline__ void fc_body(const float* __restrict__ hfin, const TW* __restrict__ Wfc,
                                        const TW* __restrict__ bfc, TW* __restrict__ out) {
  const int idx = threadIdx.x;
  const int b = idx >> 1;
  const int cc = idx & 1;
  float acc = ldf(bfc, cc);
  for (int k = 0; k < Hn; ++k) acc += hfin[(0 * Bn + b) * Hn + k] * ldf(Wfc, k * 2 + cc);
  for (int k = 0; k < Hn; ++k) acc += hfin[(1 * Bn + b) * Hn + k] * ldf(Wfc, (Hn + k) * 2 + cc);
  if constexpr (sizeof(TW) == 2) {
    out[b * 2 + cc] = __float2bfloat16(acc);
  } else {
    out[b * 2 + cc] = acc;
  }
}

__global__ void k_fc(const float* __restrict__ hfin, const void* __restrict__ Wfc,
                     const void* __restrict__ bfc, const int* __restrict__ flag,
                     void* __restrict__ out) {
  if (flag[0]) {
    fc_body<float>(hfin, (const float*)Wfc, (const float*)bfc, (float*)out);
  } else {
    fc_body<__hip_bfloat16>(hfin, (const __hip_bfloat16*)Wfc, (const __hip_bfloat16*)bfc,
                            (__hip_bfloat16*)out);
  }
}

// ---------------------------------------------------------------------------
extern "C" void kernel_launch(void* const* d_in, const int* in_sizes, int n_in,
                              void* d_out, int out_size, void* d_ws, size_t ws_size,
                              hipStream_t stream) {
  const int* x = (const int*)d_in[0];
  const void* E = d_in[1];
  const void* Wf0 = d_in[2];
  const void* bf0 = d_in[3];
  const void* Wb0 = d_in[4];
  const void* bb0 = d_in[5];
  const void* Wf1 = d_in[6];
  const void* bf1 = d_in[7];
  const void* Wb1 = d_in[8];
  const void* bb1 = d_in[9];
  const void* Wfc = d_in[10];
  const void* bfc = d_in[11];

  char* ws = (char*)d_ws;
  int* flag = (int*)ws;             // @0
  int* lengths = (int*)(ws + 256);

  const size_t MB = 1ull << 20;
  const size_t KB = 1024;

  k_detect<<<1, 256, 0, stream>>>((const unsigned short*)E, flag);
  k_lengths<<<Bn, 256, 0, stream>>>(x, lengths);

  // pick largest xproj chunk (Tc timesteps/dir, Tc*0.5 MB) that fits ws
  int Tc = 0;
  {
    const size_t fixed = 73 * MB + MB;  // weights/state/flags/seq0 + slack
    const int cands[7] = {1024, 512, 256, 128, 64, 32, 16};
    for (int i = 0; i < 7; ++i)
      if (fixed + (size_t)cands[i] * 512 * KB <= ws_size) { Tc = cands[i]; break; }
  }

  if (Tc > 0) {
    float* biasbuf = (float*)(ws + 4096);                    // 16 KB
    __hip_bfloat16* whT = (__hip_bfloat16*)(ws + 1 * MB);    // [4][1024][256] = 2 MB
    __hip_bfloat16* wxT0 = (__hip_bfloat16*)(ws + 3 * MB);   // [2][1024][256] = 1 MB
    __hip_bfloat16* wxT1 = (__hip_bfloat16*)(ws + 4 * MB);   // [2][1024][512] = 2 MB
    __hip_bfloat16* hgs = (__hip_bfloat16*)(ws + 6 * MB);    // [2][2][4][64][64] = 128 KB
    float* cstate0 = (float*)(ws + 6 * MB + 128 * KB);       // 128 KB
    float* hstate0 = (float*)(ws + 6 * MB + 256 * KB);       // 128 KB
    float* cstate1 = (float*)(ws + 6 * MB + 384 * KB);       // 128 KB
    float* hstate1 = (float*)(ws + 6 * MB + 512 * KB);       // 128 KB
    unsigned* flags = (unsigned*)(ws + 7 * MB);              // 2 layers x 512 KB = 1 MB
    __hip_bfloat16* seq0 = (__hip_bfloat16*)(ws + 8 * MB);   // [1024][64][512] = 64 MB
    float* xproj = (float*)(ws + 73 * MB);                   // [2][Tc][64][1024] f32
    unsigned* flags0 = flags;
    unsigned* flags1 = flags + (512 * KB / 4);

    k_prep_small<<<1, 256, 0, stream>>>(bf0, bb0, bf1, bb1, flag, biasbuf);
    k_prepw<<<dim3(12, 16, 4), 256, 0, stream>>>(Wf0, Wb0, Wf1, Wb1, flag, whT, wxT0, wxT1);
    hipMemsetAsync(flags, 0, 1 * MB, stream);

    const int P = Tn / Tc;
    // layer 0
    for (int p = 0; p < P; ++p) {
      const int s0 = p * Tc;
      const int t0f = s0, t0b = Tn - s0 - Tc;
      k_xproj<0><<<dim3(Tc, 16, 2), 256, 0, stream>>>(x, E, flag, nullptr, wxT0, biasbuf, xproj,
                                                      t0f, t0b, Tc);
      k_lstm_fast<true><<<8, 256, 0, stream>>>(whT, xproj, lengths, flags0, hgs, cstate0, hstate0,
                                               seq0, s0, Tc);
    }
    // layer 1
    for (int p = 0; p < P; ++p) {
      const int s0 = p * Tc;
      const int t0f = s0, t0b = Tn - s0 - Tc;
      k_xproj<1><<<dim3(Tc, 16, 2), 256, 0, stream>>>(x, E, flag, seq0, wxT1, biasbuf + 2048,
                                                      xproj, t0f, t0b, Tc);
      k_lstm_fast<false><<<8, 256, 0, stream>>>(whT + 2 * 1024 * 256, xproj, lengths, flags1, hgs,
                                                cstate1, hstate1, nullptr, s0, Tc);
    }
    k_fc<<<1, 128, 0, stream>>>(hstate1, Wfc, bfc, flag, d_out);
  } else {
    // slow fallback (round-2 passing path)
    __hip_bfloat16* seq0 = (__hip_bfloat16*)(ws + 64 * 1024);
    const size_t seq0_bytes = (size_t)Bn * Tn * 2 * Hn * sizeof(__hip_bfloat16);
    float* hfin = (float*)(ws + 64 * 1024 + seq0_bytes);
    k_lstm<Dn, true><<<2 * Bn, 256, 0, stream>>>(x, E, nullptr, Wf0, bf0, Wb0, bb0, lengths, flag,
                                                 seq0, nullptr);
    k_lstm<2 * Hn, false><<<2 * Bn, 256, 0, stream>>>(x, E, seq0, Wf1, bf1, Wb1, bb1, lengths,
                                                      flag, nullptr, hfin);
    k_fc<<<1, 128, 0, stream>>>(hfin, Wfc, bfc, flag, d_out);
  }
}